// Round 10
// baseline (127.071 us; speedup 1.0000x reference)
//
#include <hip/hip_runtime.h>
#include <math.h>

#define HOP     200
#define NB      32
#define TLEN    480000
#define NSEGQ   2400                   // output segments per row
#define SEG     60                     // segments produced per K1 block
#define NTILE   (NSEGQ / SEG)          // 40
#define NSEGP   (SEG + 6)              // 66 staged segments: [q0-3, q0+62]

#define DLT  0.00785398163397448f      // 2*pi/800
// cos/sin of k*DLT, k=1..3 (within-float4 angle stepping)
#define C1K  0.99996915760f
#define S1K  0.00785390090f
#define C2K  0.99987663248f
#define S2K  0.01570731731f
#define C3K  0.99972243010f
#define S3K  0.02355976470f
// rotation by 40*DLT = pi/10 (between successive float4s of one thread)
#define C40  0.95105651629515f
#define S40  0.30901699437495f

typedef float floatx4 __attribute__((ext_vector_type(4)));

// Analytic collapse (validated R1-R9):
//   out[p] = 0.75*x[t] + A'(q,par) - R'(q,par)*cos(p*DLT - psi)  [+ edge w^2 corr]
// K1 computes segc=(A',R',psi) per (segment,parity); K2 is a barrier-free
// pure stream (the R6-R9 plateau was synchronized barrier drains, not BW).

// K1: x -> segc. Register-accumulated partials, 2 barriers, coalesced segc store.
__global__ __launch_bounds__(256) void seg_const(const float* __restrict__ x,
                                                 float4* __restrict__ segc) {
    __shared__ float part[NSEGP][10][7];    // pad 6->7: breaks 4-way bank aliasing
    __shared__ float pg[NSEGP][6];

    const int qb = blockIdx.x;              // [0, NTILE)
    const int b  = blockIdx.y;
    const int q0 = qb * SEG;
    const float* xb = x + (size_t)b * TLEN;

    // Phase A: per-(segment, decade) basis partials in registers
    for (int u = threadIdx.x; u < NSEGP * 10; u += 256) {
        const int s = u / 10;
        const int k = u - 10 * s;
        const int g = q0 - 3 + s;           // [-3, 2402]
        const int gm = (g + 4) & 3;
        float c0, sn0;
        __sincosf((float)(gm * 200 + 4 * k) * DLT, &sn0, &c0);
        float p1e = 0.f, p1o = 0.f, pce = 0.f, pco = 0.f, pse = 0.f, pso = 0.f;
        const bool inb = (g >= 0) && (g <= 2399);
        float4 ve;
        if (!inb) {                         // edge-pad segment: constant x
            const float xe = (g < 0) ? xb[0] : xb[TLEN - 1];
            ve = make_float4(xe, xe, xe, xe);
        }
#pragma unroll
        for (int i = 0; i < 5; ++i) {
            float4 v;
            if (inb) v = ((const float4*)(xb + 200 * g))[k + 10 * i];
            else     v = ve;
            const float c1 = c0 * C1K - sn0 * S1K, s1 = sn0 * C1K + c0 * S1K;
            const float c2 = c0 * C2K - sn0 * S2K, s2 = sn0 * C2K + c0 * S2K;
            const float c3 = c0 * C3K - sn0 * S3K, s3 = sn0 * C3K + c0 * S3K;
            p1e += v.x + v.z;             p1o += v.y + v.w;
            pce += c0 * v.x + c2 * v.z;   pco += c1 * v.y + c3 * v.w;
            pse += sn0 * v.x + s2 * v.z;  pso += s1 * v.y + s3 * v.w;
            const float cn = c0 * C40 - sn0 * S40;     // advance 40 samples
            sn0 = sn0 * C40 + c0 * S40;  c0 = cn;
        }
        part[s][k][0] = p1e;  part[s][k][1] = p1o;
        part[s][k][2] = pce;  part[s][k][3] = pco;
        part[s][k][4] = pse;  part[s][k][5] = pso;
    }
    __syncthreads();

    // Phase B: fold decades
    for (int u = threadIdx.x; u < NSEGP * 6; u += 256) {
        const int s = u / 6;
        const int c = u - 6 * s;
        float a = 0.f;
#pragma unroll
        for (int k = 0; k < 10; ++k) a += part[s][k][c];
        pg[s][c] = a;
    }
    __syncthreads();

    // Phase C: (A,C,D) -> (A',R',psi), straight to global (coalesced float4)
    if (threadIdx.x < 2 * SEG) {
        const int par = threadIdx.x & 1;
        const int ql  = threadIdx.x >> 1;
        const int q   = q0 + ql;
        float A = 0.f, C = 0.f, D = 0.f;
#pragma unroll
        for (int df = -1; df <= 2; ++df) {
            const int f = q + df;
            if (f < 0 || f > 2400) continue;     // boundary frame mask
            const int ls0 = f - q0 + 1;          // local index of g=f-2
            float sp1 = 0.f, spc = 0.f, sps = 0.f;
#pragma unroll
            for (int kk = 0; kk < 4; ++kk) {
                const float* rec = pg[ls0 + kk];
                sp1 += rec[par];  spc += rec[2 + par];  sps += rec[4 + par];
            }
            const int fm = f & 3;
            const float tr = (fm == 0) ? spc : (fm == 1) ? sps : (fm == 2) ? -spc : -sps;
            const float S = 0.5f * sp1 + 0.5f * tr;
            A += S;
            if (fm == 0) C += S; else if (fm == 2) C -= S;
            else if (fm == 1) D += S; else D -= S;
        }
        segc[((size_t)b * NSEGQ + q) * 2 + par] =
            make_float4(A * (1.0f / 1600.0f),
                        sqrtf(C * C + D * D) * (1.0f / 1600.0f),
                        atan2f(D, C), 0.f);
    }
}

// K2: barrier-free, LDS-free pure stream. One float4 of out per iteration.
__global__ __launch_bounds__(256) void synth(const float* __restrict__ x,
                                             const float4* __restrict__ segc,
                                             float* __restrict__ out) {
    const int total = NB * (TLEN / 4);                 // 3.84M float4s
    const float4* x4 = (const float4*)x;
    floatx4* o4 = (floatx4*)out;
    for (int i = blockIdx.x * 256 + threadIdx.x; i < total; i += gridDim.x * 256) {
        const int b  = i / (TLEN / 4);
        const int j4 = i - b * (TLEN / 4);
        const int q  = j4 / 50;                        // output segment [0, 2400)
        const float4 ce = segc[((size_t)b * NSEGQ + q) * 2];     // broadcast (50 thr share)
        const float4 co = segc[((size_t)b * NSEGQ + q) * 2 + 1];
        const float4 xv = x4[i];                       // L3-hot (K1 streamed x)
        const int pm = (4 * j4 + 400) % 800;
        const float xa[4] = {xv.x, xv.y, xv.z, xv.w};
        float r[4];
#pragma unroll
        for (int c = 0; c < 4; ++c) {
            const float4 cc = (c & 1) ? co : ce;
            r[c] = 0.75f * xa[c] + cc.x - cc.y * __cosf((float)(pm + c) * DLT - cc.z);
        }
        if (q == 0) {                                  // missing-frame w^2 correction
#pragma unroll
            for (int c = 0; c < 4; ++c) {
                const float wm = 0.5f + 0.5f * __sinf((float)(pm + c) * DLT);
                r[c] -= 0.5f * wm * wm * xa[c];
            }
        }
        if (q == NSEGQ - 1) {
#pragma unroll
            for (int c = 0; c < 4; ++c) {
                const float wm = 0.5f - 0.5f * __sinf((float)(pm + c) * DLT);
                r[c] -= 0.5f * wm * wm * xa[c];
            }
        }
        floatx4 rv = {r[0], r[1], r[2], r[3]};
        __builtin_nontemporal_store(rv, &o4[i]);
    }
}

extern "C" void kernel_launch(void* const* d_in, const int* in_sizes, int n_in,
                              void* d_out, int out_size, void* d_ws, size_t ws_size,
                              hipStream_t stream) {
    const float* x = (const float*)d_in[0];
    float* out = (float*)d_out;
    float4* segc = (float4*)d_ws;     // NB*2400*2 float4 = 2.46 MB

    seg_const<<<dim3(NTILE, NB), dim3(256), 0, stream>>>(x, segc);
    synth<<<dim3(2048), dim3(256), 0, stream>>>(x, segc, out);
}